// Round 1
// baseline (906.435 us; speedup 1.0000x reference)
//
#include <hip/hip_runtime.h>
#include <hip/hip_bf16.h>
#include <cstdint>

#define SEQ 192
#define DIMF 512
#define PROJ_COLS 2560

// ---------------- LayerNorm ----------------
__global__ void ln_kernel(const float* __restrict__ x, const float* __restrict__ w,
                          const float* __restrict__ b, float* __restrict__ xn) {
  int r = blockIdx.x, tid = threadIdx.x;
  const float* xr = x + (size_t)r * DIMF;
  float v0 = xr[tid], v1 = xr[tid + 256];
  float s = v0 + v1, s2 = v0 * v0 + v1 * v1;
#pragma unroll
  for (int off = 32; off > 0; off >>= 1) {
    s += __shfl_down(s, off);
    s2 += __shfl_down(s2, off);
  }
  __shared__ float redS[4], redS2[4];
  int wave = tid >> 6, lane = tid & 63;
  if (lane == 0) { redS[wave] = s; redS2[wave] = s2; }
  __syncthreads();
  float S = redS[0] + redS[1] + redS[2] + redS[3];
  float S2 = redS2[0] + redS2[1] + redS2[2] + redS2[3];
  float mean = S * (1.0f / DIMF);
  float var = S2 * (1.0f / DIMF) - mean * mean;
  float rstd = rsqrtf(var + 1e-5f);
  float* xnr = xn + (size_t)r * DIMF;
  xnr[tid]       = (v0 - mean) * rstd * w[tid] + b[tid];
  xnr[tid + 256] = (v1 - mean) * rstd * w[tid + 256] + b[tid + 256];
}

// ---------------- generic tiled f32 GEMM: C = A @ B(^T) (+bias) ----------------
// 64x64 tile, K-step 16, 256 threads, 4x4 micro-tile. All dims must be multiples
// of tile sizes (true for every call here). lda/ldb and k offsets are %4==0 so
// float4 loads are aligned.
template <bool TRANSB, bool HAS_BIAS>
__global__ __launch_bounds__(256) void gemm_kernel(
    const float* __restrict__ A, const float* __restrict__ B, float* __restrict__ C,
    const float* __restrict__ bias, int M, int N, int K, int lda, int ldb, int ldc,
    long strideA, long strideB, long strideC) {
  int z = blockIdx.z;
  A += (long)z * strideA; B += (long)z * strideB; C += (long)z * strideC;
  int n0 = blockIdx.x * 64, m0 = blockIdx.y * 64;
  int tid = threadIdx.x, tx = tid & 15, ty = tid >> 4;
  __shared__ float As[64][20];
  __shared__ float Bs[16][68];
  float acc[4][4] = {};
  for (int k0 = 0; k0 < K; k0 += 16) {
    {
      int id = tid * 4;
      int row = id >> 4, kk = id & 15;
      const float* ap = A + (long)(m0 + row) * lda + k0 + kk;
      float4 av = *(const float4*)ap;
      *(float4*)&As[row][kk] = av;
    }
    if (TRANSB) {
      int id = tid * 4;
      int col = id >> 4, kk = id & 15;
      const float* bp = B + (long)(n0 + col) * ldb + k0 + kk;
      float4 bv = *(const float4*)bp;
      Bs[kk][col] = bv.x; Bs[kk + 1][col] = bv.y; Bs[kk + 2][col] = bv.z; Bs[kk + 3][col] = bv.w;
    } else {
#pragma unroll
      for (int i = 0; i < 4; i++) {
        int id = i * 256 + tid;
        int col = id & 63, kk = id >> 6;
        Bs[kk][col] = B[(long)(k0 + kk) * ldb + n0 + col];
      }
    }
    __syncthreads();
#pragma unroll
    for (int kk = 0; kk < 16; kk++) {
      float a_reg[4], b_reg[4];
#pragma unroll
      for (int i = 0; i < 4; i++) a_reg[i] = As[ty + 16 * i][kk];
#pragma unroll
      for (int j = 0; j < 4; j++) b_reg[j] = Bs[kk][tx + 16 * j];
#pragma unroll
      for (int i = 0; i < 4; i++)
#pragma unroll
        for (int j = 0; j < 4; j++) acc[i][j] += a_reg[i] * b_reg[j];
    }
    __syncthreads();
  }
#pragma unroll
  for (int i = 0; i < 4; i++) {
    int m = m0 + ty + 16 * i;
#pragma unroll
    for (int j = 0; j < 4; j++) {
      int n = n0 + tx + 16 * j;
      float v = acc[i][j];
      if (HAS_BIAS) v += bias[n];
      C[(long)m * ldc + n] = v;
    }
  }
}

// ---------------- bsum[q][j] = sum_h b_[q,h,j] ----------------
__global__ void bsum_kernel(const float* __restrict__ proj, float* __restrict__ bsum) {
  int q = blockIdx.x, j = threadIdx.x;  // 64 threads
  const float* pr = proj + (size_t)q * PROJ_COLS + 512 + j;
  float s = 0.f;
#pragma unroll
  for (int h = 0; h < 8; h++) s += pr[h * 64];
  bsum[q * 64 + j] = s;
}

// ---------------- WK2[(h*64+k)][(i*64+j)] = W_K[h][i][j][k] ----------------
__global__ void wk2_kernel(const float* __restrict__ WK, float* __restrict__ WK2) {
  int o = blockIdx.x * 256 + threadIdx.x;  // 2M elements
  int n = o & 4095, kk = o >> 12;
  int i = n >> 6, j = n & 63, h = kk >> 6, k = kk & 63;
  WK2[o] = WK[(((h * 64 + i) * 64 + j) * 64) + k];
}

// ---------------- ecum[h][p][g] = sum_{q<=p} e[q,h,g] ----------------
__global__ void ecum_kernel(const float* __restrict__ proj, float* __restrict__ ecum) {
  int h = blockIdx.x, g = threadIdx.x;  // 64 threads
  float run = 0.f;
  for (int p = 0; p < SEQ; p++) {
    run += proj[(size_t)p * PROJ_COLS + 2048 + h * 64 + g];
    ecum[((size_t)h * SEQ + p) * 64 + g] = run;
  }
}

// ---------------- Vm[h][f] = sum_{p,g} t[h,p,g,f] * ecum[h,p,g] ----------------
__global__ void vm_kernel(const float* __restrict__ t, const float* __restrict__ ecum,
                          float* __restrict__ Vm) {
  int pt = blockIdx.x, h = blockIdx.y;
  int tid = threadIdx.x, f = tid & 63, gg = tid >> 6;
  float acc = 0.f;
  for (int pp = 0; pp < 16; pp++) {
    int p = pt * 16 + pp;
    const float* tp = t + ((size_t)(h * SEQ + p) * 64) * 64;
    const float* ep = ecum + (size_t)(h * SEQ + p) * 64;
#pragma unroll
    for (int gi = 0; gi < 16; gi++) {
      int g = gg * 16 + gi;
      acc += tp[g * 64 + f] * ep[g];
    }
  }
  __shared__ float red[256];
  red[tid] = acc;
  __syncthreads();
  if (gg == 0) {
    float s = red[f] + red[64 + f] + red[128 + f] + red[192 + f];
    atomicAdd(&Vm[h * 64 + f], s);
  }
}

// ---------------- fused scores + exp + ew per (h, r) ----------------
// s[p,q] = (1/64) * sum_i a[p,h,i] * step2[r,i,q];  w = (p<q) ? exp(s) : 0
// ew[hb,r,p,g] = sum_q w[p,q] * e[q,h,g];  Lsum[h,r] = sum w
__global__ __launch_bounds__(256) void attn_kernel(
    const float* __restrict__ proj, const float* __restrict__ step2,
    float* __restrict__ ew, float* __restrict__ Lsum, int h0) {
  int r = blockIdx.x, hb = blockIdx.y, h = h0 + hb;
  int tid = threadIdx.x;
  __shared__ float st2[64 * 192];  // [i][q]
  __shared__ float Sm[8 * 198];    // [p_l][q], padded stride 198
  __shared__ float At[8 * 66];     // [p_l][i], padded stride 66
  __shared__ float red[256];
  for (int idx = tid; idx < 64 * 192; idx += 256)
    st2[idx] = step2[(size_t)(r * 64) * 192 + idx];
  __syncthreads();

  int p_l = tid & 7, qg = tid >> 3;        // scores: q = qg*6 + jj (wave-contiguous q)
  int p_l2 = tid >> 5, g0 = (tid & 31) * 2;  // ew phase
  int wave = tid >> 6;
  float lpart = 0.f;
  const float scale = 1.0f / 64.0f;

  for (int pt = 0; pt < 24; pt++) {
    for (int idx = tid; idx < 512; idx += 256) {
      int pl = idx >> 6, i = idx & 63;
      At[pl * 66 + i] = proj[(size_t)(pt * 8 + pl) * PROJ_COLS + h * 64 + i];
    }
    __syncthreads();
    int p = pt * 8 + p_l;
    // wave-uniform skip: this wave's max q <= tile's min p -> everything masked
    bool active = (wave * 48 + 47) > (pt * 8);
    float accq[6] = {0.f, 0.f, 0.f, 0.f, 0.f, 0.f};
    if (active) {
      for (int i = 0; i < 64; i++) {
        float av = At[p_l * 66 + i];
        const float* s2p = &st2[i * 192 + qg * 6];
#pragma unroll
        for (int jj = 0; jj < 6; jj++) accq[jj] += av * s2p[jj];
      }
    }
#pragma unroll
    for (int jj = 0; jj < 6; jj++) {
      int q = qg * 6 + jj;
      float wv = (active && q > p) ? __expf(accq[jj] * scale) : 0.f;
      Sm[p_l * 198 + q] = wv;
      lpart += wv;
    }
    __syncthreads();
    // ew phase: q <= pt*8 all have w == 0, skip them
    float e0 = 0.f, e1 = 0.f;
    for (int q = pt * 8 + 1; q < SEQ; q++) {
      float wv = Sm[p_l2 * 198 + q];
      const float* eb = proj + (size_t)q * PROJ_COLS + 2048 + h * 64;
      float2 evv = *(const float2*)(eb + g0);
      e0 += wv * evv.x;
      e1 += wv * evv.y;
    }
    int p2 = pt * 8 + p_l2;
    float2 o; o.x = e0; o.y = e1;
    *(float2*)&ew[((((size_t)hb * SEQ + r) * SEQ) + p2) * 64 + g0] = o;
    __syncthreads();
  }
  red[tid] = lpart;
  __syncthreads();
  for (int off2 = 128; off2 > 0; off2 >>= 1) {
    if (tid < off2) red[tid] += red[tid + off2];
    __syncthreads();
  }
  if (tid == 0) Lsum[h * SEQ + r] = red[0];
}

// ---------------- split-K z GEMM: Zpart[h,ks][r][f] = ew[hb,r,:]chunk @ t[h,:,:]chunk ----------------
__global__ __launch_bounds__(256) void zgemm_kernel(
    const float* __restrict__ ew, const float* __restrict__ t, float* __restrict__ Zpart,
    int h0) {
  int hb = blockIdx.x, ks = blockIdx.y, h = h0 + hb;
  int tid = threadIdx.x;
  int f0 = (tid & 15) * 4, rg = tid >> 4;
  __shared__ float ewT[16 * 193];
  __shared__ float tT[16 * 64];
  float acc[12][4] = {};
  for (int k0 = 0; k0 < 384; k0 += 16) {
    int pgb = ks * 384 + k0;
#pragma unroll
    for (int jl = 0; jl < 12; jl++) {
      int id = jl * 256 + tid;
      int kk = id & 15, rr = id >> 4;
      ewT[kk * 193 + rr] = ew[((size_t)hb * SEQ + rr) * 12288 + pgb + kk];
    }
#pragma unroll
    for (int jl = 0; jl < 4; jl++) {
      int id = jl * 256 + tid;
      int ff = id & 63, kk = id >> 6;
      tT[kk * 64 + ff] = t[(size_t)h * 786432 + (size_t)(pgb + kk) * 64 + ff];
    }
    __syncthreads();
#pragma unroll
    for (int kk = 0; kk < 16; kk++) {
      float4 tv = *(const float4*)&tT[kk * 64 + f0];
#pragma unroll
      for (int rr = 0; rr < 12; rr++) {
        float evv = ewT[kk * 193 + rg * 12 + rr];
        acc[rr][0] += evv * tv.x; acc[rr][1] += evv * tv.y;
        acc[rr][2] += evv * tv.z; acc[rr][3] += evv * tv.w;
      }
    }
    __syncthreads();
  }
#pragma unroll
  for (int rr = 0; rr < 12; rr++) {
    int r = rg * 12 + rr;
    float4 o; o.x = acc[rr][0]; o.y = acc[rr][1]; o.z = acc[rr][2]; o.w = acc[rr][3];
    *(float4*)&Zpart[(((size_t)h * 32 + ks) * SEQ + r) * 64 + f0] = o;
  }
}

// ---------------- epilogue: z = (sum_ks Zpart + Vm) / (Lsum + 18528) ----------------
__global__ void epi_kernel(const float* __restrict__ Zpart, const float* __restrict__ Vm,
                           const float* __restrict__ Lsum, float* __restrict__ z) {
  int r = blockIdx.x, tid = threadIdx.x;
  for (int c = tid; c < 512; c += 256) {
    int h = c >> 6, f = c & 63;
    float s = 0.f;
    for (int ks = 0; ks < 32; ks++)
      s += Zpart[(((size_t)h * 32 + ks) * SEQ + r) * 64 + f];
    float L = Lsum[h * SEQ + r] + 18528.0f;  // masked mass: 18528 entries with w == 1.0f
    z[(size_t)r * 512 + c] = (s + Vm[c]) / L;
  }
}

// ---------------- workspace layout (floats) ----------------
static const size_t OFF_XN = 0;                 //  98304
static const size_t OFF_PROJ = 98304;           // 491520
static const size_t OFF_BSUM = 589824;          //  12288
static const size_t OFF_WK2 = 602112;           // 2097152
static const size_t OFF_STEP1 = 2699264;        // 786432
static const size_t OFF_STEP2 = 3485696;        // 2359296
static const size_t OFF_T = 5844992;            // 6291456
static const size_t OFF_ECUM = 12136448;        //  98304
static const size_t OFF_VM = 12234752;          //    512
static const size_t OFF_LSUM = 12235264;        //   1536
static const size_t OFF_Z = 12236800;           //  98304
static const size_t OFF_ZPART = 12335104;       // 3145728
static const size_t OFF_EW = 15480832;          // 18874368 (full mode)
static const size_t TOTAL_FULL = 34355200;      // floats
static const size_t TOTAL_PERH = 15480832;      // floats (ew aliases WK2/step1 region)

extern "C" void kernel_launch(void* const* d_in, const int* in_sizes, int n_in,
                              void* d_out, int out_size, void* d_ws, size_t ws_size,
                              hipStream_t stream) {
  (void)in_sizes; (void)n_in; (void)out_size;
  const float* x = (const float*)d_in[0];
  const float* ln_w = (const float*)d_in[1];
  const float* ln_b = (const float*)d_in[2];
  const float* W_abcde = (const float*)d_in[3];
  const float* b_abcde = (const float*)d_in[4];
  const float* W_K = (const float*)d_in[5];
  const float* W_V = (const float*)d_in[6];
  const float* W_out = (const float*)d_in[7];
  const float* b_out = (const float*)d_in[8];
  float* out = (float*)d_out;
  float* ws = (float*)d_ws;

  float* xn = ws + OFF_XN;
  float* proj = ws + OFF_PROJ;
  float* bsum = ws + OFF_BSUM;
  float* wk2 = ws + OFF_WK2;
  float* step1 = ws + OFF_STEP1;
  float* step2 = ws + OFF_STEP2;
  float* tbuf = ws + OFF_T;
  float* ecum = ws + OFF_ECUM;
  float* Vm = ws + OFF_VM;
  float* Lsum = ws + OFF_LSUM;
  float* z = ws + OFF_Z;
  float* Zpart = ws + OFF_ZPART;

  bool full = ws_size >= TOTAL_FULL * sizeof(float);
  float* ew = full ? ws + OFF_EW : ws + OFF_WK2;  // per-h mode: reuse dead WK2/step1 space

  ln_kernel<<<SEQ, 256, 0, stream>>>(x, ln_w, ln_b, xn);
  // proj = xn @ W_abcde^T + b_abcde  [192 x 2560]
  gemm_kernel<true, true><<<dim3(40, 3, 1), 256, 0, stream>>>(
      xn, W_abcde, proj, b_abcde, 192, 2560, 512, 512, 512, 2560, 0, 0, 0);
  bsum_kernel<<<SEQ, 64, 0, stream>>>(proj, bsum);
  wk2_kernel<<<8192, 256, 0, stream>>>(W_K, wk2);
  // step1 = c @ WK2  [192 x 4096]
  gemm_kernel<false, false><<<dim3(64, 3, 1), 256, 0, stream>>>(
      proj + 1024, wk2, step1, nullptr, 192, 4096, 512, 2560, 4096, 4096, 0, 0, 0);
  // step2[(r,i)][q] = step1view @ bsum^T  [12288 x 192]
  gemm_kernel<true, false><<<dim3(3, 192, 1), 256, 0, stream>>>(
      step1, bsum, step2, nullptr, 12288, 192, 64, 64, 64, 192, 0, 0, 0);
  // t[h] = d_h @ W_V[h]  [192 x 4096] x8
  gemm_kernel<false, false><<<dim3(64, 3, 8), 256, 0, stream>>>(
      proj + 1536, W_V, tbuf, nullptr, 192, 4096, 64, 2560, 4096, 4096, 64, 262144, 786432);
  ecum_kernel<<<8, 64, 0, stream>>>(proj, ecum);
  hipMemsetAsync(Vm, 0, 512 * sizeof(float), stream);
  vm_kernel<<<dim3(12, 8), 256, 0, stream>>>(tbuf, ecum, Vm);

  if (full) {
    attn_kernel<<<dim3(SEQ, 8), 256, 0, stream>>>(proj, step2, ew, Lsum, 0);
    zgemm_kernel<<<dim3(8, 32), 256, 0, stream>>>(ew, tbuf, Zpart, 0);
  } else {
    for (int h = 0; h < 8; h++) {
      attn_kernel<<<dim3(SEQ, 1), 256, 0, stream>>>(proj, step2, ew, Lsum, h);
      zgemm_kernel<<<dim3(1, 32), 256, 0, stream>>>(ew, tbuf, Zpart, h);
    }
  }
  epi_kernel<<<SEQ, 256, 0, stream>>>(Zpart, Vm, Lsum, z);
  // out = z @ W_out^T + b_out  [192 x 512]
  gemm_kernel<true, true><<<dim3(8, 3, 1), 256, 0, stream>>>(
      z, W_out, out, b_out, 192, 512, 512, 512, 512, 512, 0, 0, 0);
}

// Round 2
// 324.109 us; speedup vs baseline: 2.7967x; 2.7967x over previous
//
#include <hip/hip_runtime.h>
#include <hip/hip_bf16.h>
#include <cstdint>

#define SEQ 192
#define DIMF 512
#define PROJ_COLS 2560

typedef float f32x4 __attribute__((ext_vector_type(4)));
typedef __bf16 bf16x8 __attribute__((ext_vector_type(8)));
typedef unsigned short u16;

#define MFMA_BF16(a, b, c) __builtin_amdgcn_mfma_f32_16x16x32_bf16(a, b, c, 0, 0, 0)

__device__ __forceinline__ u16 f2bf(float f) {
  unsigned u = __float_as_uint(f);
  unsigned r = (u + 0x7FFFu + ((u >> 16) & 1u)) >> 16;
  return (u16)r;
}

// ---------------- LayerNorm ----------------
__global__ void ln_kernel(const float* __restrict__ x, const float* __restrict__ w,
                          const float* __restrict__ b, float* __restrict__ xn) {
  int r = blockIdx.x, tid = threadIdx.x;
  const float* xr = x + (size_t)r * DIMF;
  float v0 = xr[tid], v1 = xr[tid + 256];
  float s = v0 + v1, s2 = v0 * v0 + v1 * v1;
#pragma unroll
  for (int off = 32; off > 0; off >>= 1) {
    s += __shfl_down(s, off);
    s2 += __shfl_down(s2, off);
  }
  __shared__ float redS[4], redS2[4];
  int wave = tid >> 6, lane = tid & 63;
  if (lane == 0) { redS[wave] = s; redS2[wave] = s2; }
  __syncthreads();
  float S = redS[0] + redS[1] + redS[2] + redS[3];
  float S2 = redS2[0] + redS2[1] + redS2[2] + redS2[3];
  float mean = S * (1.0f / DIMF);
  float var = S2 * (1.0f / DIMF) - mean * mean;
  float rstd = rsqrtf(var + 1e-5f);
  float* xnr = xn + (size_t)r * DIMF;
  xnr[tid]       = (v0 - mean) * rstd * w[tid] + b[tid];
  xnr[tid + 256] = (v1 - mean) * rstd * w[tid + 256] + b[tid + 256];
}

// ---------------- generic tiled f32 GEMM: C = A @ B(^T) (+bias) ----------------
template <bool TRANSB, bool HAS_BIAS>
__global__ __launch_bounds__(256) void gemm_kernel(
    const float* __restrict__ A, const float* __restrict__ B, float* __restrict__ C,
    const float* __restrict__ bias, int M, int N, int K, int lda, int ldb, int ldc,
    long strideA, long strideB, long strideC) {
  int z = blockIdx.z;
  A += (long)z * strideA; B += (long)z * strideB; C += (long)z * strideC;
  int n0 = blockIdx.x * 64, m0 = blockIdx.y * 64;
  int tid = threadIdx.x, tx = tid & 15, ty = tid >> 4;
  __shared__ float As[64][20];
  __shared__ float Bs[16][68];
  float acc[4][4] = {};
  for (int k0 = 0; k0 < K; k0 += 16) {
    {
      int id = tid * 4;
      int row = id >> 4, kk = id & 15;
      const float* ap = A + (long)(m0 + row) * lda + k0 + kk;
      float4 av = *(const float4*)ap;
      *(float4*)&As[row][kk] = av;
    }
    if (TRANSB) {
      int id = tid * 4;
      int col = id >> 4, kk = id & 15;
      const float* bp = B + (long)(n0 + col) * ldb + k0 + kk;
      float4 bv = *(const float4*)bp;
      Bs[kk][col] = bv.x; Bs[kk + 1][col] = bv.y; Bs[kk + 2][col] = bv.z; Bs[kk + 3][col] = bv.w;
    } else {
#pragma unroll
      for (int i = 0; i < 4; i++) {
        int id = i * 256 + tid;
        int col = id & 63, kk = id >> 6;
        Bs[kk][col] = B[(long)(k0 + kk) * ldb + n0 + col];
      }
    }
    __syncthreads();
#pragma unroll
    for (int kk = 0; kk < 16; kk++) {
      float a_reg[4], b_reg[4];
#pragma unroll
      for (int i = 0; i < 4; i++) a_reg[i] = As[ty + 16 * i][kk];
#pragma unroll
      for (int j = 0; j < 4; j++) b_reg[j] = Bs[kk][tx + 16 * j];
#pragma unroll
      for (int i = 0; i < 4; i++)
#pragma unroll
        for (int j = 0; j < 4; j++) acc[i][j] += a_reg[i] * b_reg[j];
    }
    __syncthreads();
  }
#pragma unroll
  for (int i = 0; i < 4; i++) {
    int m = m0 + ty + 16 * i;
#pragma unroll
    for (int j = 0; j < 4; j++) {
      int n = n0 + tx + 16 * j;
      float v = acc[i][j];
      if (HAS_BIAS) v += bias[n];
      C[(long)m * ldc + n] = v;
    }
  }
}

// ---------------- bsum[q][j] = sum_h b_[q,h,j] ----------------
__global__ void bsum_kernel(const float* __restrict__ proj, float* __restrict__ bsum) {
  int q = blockIdx.x, j = threadIdx.x;
  const float* pr = proj + (size_t)q * PROJ_COLS + 512 + j;
  float s = 0.f;
#pragma unroll
  for (int h = 0; h < 8; h++) s += pr[h * 64];
  bsum[q * 64 + j] = s;
}

// ---------------- WK2[(h*64+k)][(i*64+j)] = W_K[h][i][j][k] ----------------
__global__ void wk2_kernel(const float* __restrict__ WK, float* __restrict__ WK2) {
  int o = blockIdx.x * 256 + threadIdx.x;
  int n = o & 4095, kk = o >> 12;
  int i = n >> 6, j = n & 63, h = kk >> 6, k = kk & 63;
  WK2[o] = WK[(((h * 64 + i) * 64 + j) * 64) + k];
}

// ---------------- ecum[h][p][g] = sum_{q<=p} e[q,h,g] ----------------
__global__ void ecum_kernel(const float* __restrict__ proj, float* __restrict__ ecum) {
  int h = blockIdx.x, g = threadIdx.x;
  float run = 0.f;
  for (int p = 0; p < SEQ; p++) {
    run += proj[(size_t)p * PROJ_COLS + 2048 + h * 64 + g];
    ecum[((size_t)h * SEQ + p) * 64 + g] = run;
  }
}

// ---------------- Vm[h][f] = sum_{p,g} t[h,p,g,f] * ecum[h,p,g] ----------------
__global__ void vm_kernel(const float* __restrict__ t, const float* __restrict__ ecum,
                          float* __restrict__ Vm) {
  int pt = blockIdx.x, h = blockIdx.y;
  int tid = threadIdx.x, f = tid & 63, gg = tid >> 6;
  float acc = 0.f;
  for (int pp = 0; pp < 16; pp++) {
    int p = pt * 16 + pp;
    const float* tp = t + ((size_t)(h * SEQ + p) * 64) * 64;
    const float* ep = ecum + (size_t)(h * SEQ + p) * 64;
#pragma unroll
    for (int gi = 0; gi < 16; gi++) {
      int g = gg * 16 + gi;
      acc += tp[g * 64 + f] * ep[g];
    }
  }
  __shared__ float red[256];
  red[tid] = acc;
  __syncthreads();
  if (gg == 0) {
    float s = red[f] + red[64 + f] + red[128 + f] + red[192 + f];
    atomicAdd(&Vm[h * 64 + f], s);
  }
}

// ---------------- convert a, e to bf16 layouts ----------------
// a_bf[h][p][i] ; eT_bf[h][g][q]
__global__ void conv_ae_kernel(const float* __restrict__ proj, u16* __restrict__ a_bf,
                               u16* __restrict__ eT_bf) {
  int p = blockIdx.x, h = blockIdx.y, t = threadIdx.x;  // 64 threads
  a_bf[((size_t)h * SEQ + p) * 64 + t] = f2bf(proj[(size_t)p * PROJ_COLS + h * 64 + t]);
  eT_bf[((size_t)h * 64 + t) * SEQ + p] = f2bf(proj[(size_t)p * PROJ_COLS + 2048 + h * 64 + t]);
}

// ---------------- s2bf[r][q][i] = bf16(step2[(r*64+i)*192 + q]) ----------------
__global__ void conv_s2_kernel(const float* __restrict__ step2, u16* __restrict__ s2bf) {
  int r = blockIdx.x, tid = threadIdx.x;
  __shared__ float ld[64 * 193];
  for (int idx = tid; idx < 12288; idx += 256) {
    int i = idx / 192, q = idx - i * 192;
    ld[i * 193 + q] = step2[((size_t)r * 64 + i) * 192 + q];
  }
  __syncthreads();
  for (int idx = tid; idx < 12288; idx += 256) {
    int q = idx >> 6, i = idx & 63;
    s2bf[(size_t)r * 12288 + idx] = f2bf(ld[i * 193 + q]);
  }
}

// ---------------- tT_bf[h][f][p*64+g] = bf16(tbuf[h][p][g*64+f]) ----------------
__global__ void conv_t_kernel(const float* __restrict__ tbuf, u16* __restrict__ tT_bf) {
  int p = blockIdx.x, h = blockIdx.y, tid = threadIdx.x;
  __shared__ float ld[64 * 65];
  const float* row = tbuf + (size_t)h * 786432 + (size_t)p * 4096;
  for (int idx = tid; idx < 4096; idx += 256) {
    int g = idx >> 6, f = idx & 63;
    ld[f * 65 + g] = row[idx];
  }
  __syncthreads();
  for (int idx = tid; idx < 4096; idx += 256) {
    int f = idx >> 6, g = idx & 63;
    tT_bf[((size_t)h * 64 + f) * 12288 + (size_t)p * 64 + g] = f2bf(ld[f * 65 + g]);
  }
}

// ---------------- MFMA fused scores+exp+ew per (h, r) ----------------
// S[p,q] = sum_i a[p,i]*step2[r,i,q]; w = (q>p)?exp(S/64):0 (bf16 via LDS);
// ew[p,g] += sum_q w[p,q]*e[q,g]. Wave w owns p in [48w,48w+48) -> w_s rows
// are wave-private, no barriers in the main loop.
__global__ __launch_bounds__(256) void attn_mfma_kernel(
    const u16* __restrict__ a_bf, const u16* __restrict__ s2bf,
    const u16* __restrict__ eT_bf, u16* __restrict__ ew_bf,
    float* __restrict__ Lsum, int h0) {
  int r = blockIdx.x, hb = blockIdx.y, h = h0 + hb;
  int tid = threadIdx.x, wave = tid >> 6, lane = tid & 63;
  int lq = lane >> 4, l16 = lane & 15;
  __shared__ u16 w_s[SEQ * 72];  // row stride 72 (144B: 16B-aligned frag reads, bank-spread)
  __shared__ float redL[4];

  bf16x8 afr[3][2];
  const u16* ab = a_bf + ((size_t)h * SEQ) * 64;
#pragma unroll
  for (int mt = 0; mt < 3; mt++)
#pragma unroll
    for (int kc = 0; kc < 2; kc++) {
      int p = wave * 48 + mt * 16 + l16;
      afr[mt][kc] = *(const bf16x8*)(ab + p * 64 + kc * 32 + lq * 8);
    }

  f32x4 ewacc[3][4];
#pragma unroll
  for (int mt = 0; mt < 3; mt++)
#pragma unroll
    for (int nt = 0; nt < 4; nt++) ewacc[mt][nt] = (f32x4){0.f, 0.f, 0.f, 0.f};

  float lpart = 0.f;
  const u16* s2r = s2bf + (size_t)r * 12288;
  const u16* eh = eT_bf + (size_t)h * 64 * SEQ;

  for (int qt = 0; qt < 3; qt++) {
    // wave-uniform skip: all (p,q) in this wave x q-tile are masked
    if (qt * 64 + 63 <= wave * 48) continue;
    bf16x8 bfr[4][2];
#pragma unroll
    for (int nt = 0; nt < 4; nt++)
#pragma unroll
      for (int kc = 0; kc < 2; kc++) {
        int q = qt * 64 + nt * 16 + l16;
        bfr[nt][kc] = *(const bf16x8*)(s2r + q * 64 + kc * 32 + lq * 8);
      }
#pragma unroll
    for (int mt = 0; mt < 3; mt++) {
#pragma unroll
      for (int nt = 0; nt < 4; nt++) {
        f32x4 s = (f32x4){0.f, 0.f, 0.f, 0.f};
        s = MFMA_BF16(afr[mt][0], bfr[nt][0], s);
        s = MFMA_BF16(afr[mt][1], bfr[nt][1], s);
        int pbase = wave * 48 + mt * 16 + lq * 4;
        int q = qt * 64 + nt * 16 + l16;
#pragma unroll
        for (int rg = 0; rg < 4; rg++) {
          int p = pbase + rg;
          float wv = (q > p) ? __expf(s[rg] * 0.015625f) : 0.f;
          lpart += wv;
          w_s[p * 72 + nt * 16 + l16] = f2bf(wv);
        }
      }
    }
    bf16x8 efr[4][2];
#pragma unroll
    for (int nt = 0; nt < 4; nt++)
#pragma unroll
      for (int kc = 0; kc < 2; kc++) {
        int g = nt * 16 + l16;
        efr[nt][kc] = *(const bf16x8*)(eh + g * SEQ + qt * 64 + kc * 32 + lq * 8);
      }
#pragma unroll
    for (int mt = 0; mt < 3; mt++) {
      int p = wave * 48 + mt * 16 + l16;
      bf16x8 wf0 = *(const bf16x8*)(&w_s[p * 72 + lq * 8]);
      bf16x8 wf1 = *(const bf16x8*)(&w_s[p * 72 + 32 + lq * 8]);
#pragma unroll
      for (int nt = 0; nt < 4; nt++) {
        ewacc[mt][nt] = MFMA_BF16(wf0, efr[nt][0], ewacc[mt][nt]);
        ewacc[mt][nt] = MFMA_BF16(wf1, efr[nt][1], ewacc[mt][nt]);
      }
    }
  }

  u16* ewout = ew_bf + ((size_t)hb * SEQ + r) * 12288;
#pragma unroll
  for (int mt = 0; mt < 3; mt++)
#pragma unroll
    for (int nt = 0; nt < 4; nt++)
#pragma unroll
      for (int rg = 0; rg < 4; rg++) {
        int p = wave * 48 + mt * 16 + lq * 4 + rg;
        int g = nt * 16 + l16;
        ewout[p * 64 + g] = f2bf(ewacc[mt][nt][rg]);
      }

#pragma unroll
  for (int off = 32; off > 0; off >>= 1) lpart += __shfl_down(lpart, off);
  if (lane == 0) redL[wave] = lpart;
  __syncthreads();
  if (tid == 0) Lsum[h * SEQ + r] = redL[0] + redL[1] + redL[2] + redL[3];
}

// ---------------- MFMA split-K z GEMM: Zpart[h][ks] = ew @ tT ----------------
__global__ __launch_bounds__(256) void zgemm_mfma_kernel(
    const u16* __restrict__ ew_bf, const u16* __restrict__ tT_bf,
    float* __restrict__ Zpart, int h0) {
  int hb = blockIdx.x, ks = blockIdx.y, h = h0 + hb;
  int tid = threadIdx.x, wave = tid >> 6, lane = tid & 63;
  int lq = lane >> 4, l16 = lane & 15;
  f32x4 acc[3][4];
#pragma unroll
  for (int mt = 0; mt < 3; mt++)
#pragma unroll
    for (int nt = 0; nt < 4; nt++) acc[mt][nt] = (f32x4){0.f, 0.f, 0.f, 0.f};
  const u16* ewb = ew_bf + (size_t)hb * SEQ * 12288;
  const u16* tb = tT_bf + (size_t)h * 64 * 12288;
  for (int kc = 0; kc < 12; kc++) {
    int kbase = ks * 384 + kc * 32 + lq * 8;
    bf16x8 af[3], bf_[4];
#pragma unroll
    for (int mt = 0; mt < 3; mt++) {
      int rr = wave * 48 + mt * 16 + l16;
      af[mt] = *(const bf16x8*)(ewb + (size_t)rr * 12288 + kbase);
    }
#pragma unroll
    for (int nt = 0; nt < 4; nt++) {
      int f = nt * 16 + l16;
      bf_[nt] = *(const bf16x8*)(tb + (size_t)f * 12288 + kbase);
    }
#pragma unroll
    for (int mt = 0; mt < 3; mt++)
#pragma unroll
      for (int nt = 0; nt < 4; nt++)
        acc[mt][nt] = MFMA_BF16(af[mt], bf_[nt], acc[mt][nt]);
  }
  float* zp = Zpart + ((size_t)(h * 32 + ks) * SEQ) * 64;
#pragma unroll
  for (int mt = 0; mt < 3; mt++)
#pragma unroll
    for (int nt = 0; nt < 4; nt++)
#pragma unroll
      for (int rg = 0; rg < 4; rg++) {
        int rr = wave * 48 + mt * 16 + lq * 4 + rg;
        int f = nt * 16 + l16;
        zp[(size_t)rr * 64 + f] = acc[mt][nt][rg];
      }
}

// ---------------- epilogue: z = (sum_ks Zpart + Vm) / (Lsum + 18528) ----------------
__global__ void epi_kernel(const float* __restrict__ Zpart, const float* __restrict__ Vm,
                           const float* __restrict__ Lsum, float* __restrict__ z) {
  int r = blockIdx.x, tid = threadIdx.x;
  for (int c = tid; c < 512; c += 256) {
    int h = c >> 6, f = c & 63;
    float s = 0.f;
    for (int ks = 0; ks < 32; ks++)
      s += Zpart[(((size_t)h * 32 + ks) * SEQ + r) * 64 + f];
    float L = Lsum[h * SEQ + r] + 18528.0f;  // masked mass: 18528 entries with w == 1.0f
    z[(size_t)r * 512 + c] = (s + Vm[c]) / L;
  }
}

// ---------------- workspace layout (float units) ----------------
static const size_t OFF_XN = 0;             //   98304
static const size_t OFF_PROJ = 98304;       //  491520
static const size_t OFF_BSUM = 589824;      //   12288
static const size_t OFF_WK2 = 602112;       // 2097152
static const size_t OFF_STEP1 = 2699264;    //  786432
static const size_t OFF_STEP2 = 3485696;    // 2359296
static const size_t OFF_T = 5844992;        // 6291456
static const size_t OFF_ECUM = 12136448;    //   98304
static const size_t OFF_VM = 12234752;      //     512
static const size_t OFF_LSUM = 12235264;    //    1536
static const size_t OFF_Z = 12236800;       //   98304
static const size_t OFF_ZPART = 12335104;   // 3145728
static const size_t OFF_ABF = 15480832;     //   49152 (u16 x 98304)
static const size_t OFF_ETBF = 15529984;    //   49152
static const size_t OFF_S2BF = 15579136;    // 1179648 (u16 x 2359296)
static const size_t OFF_TTBF = 16758784;    // 3145728 (u16 x 6291456)
static const size_t OFF_EWBF = 19904512;    // 9437184 (u16 x 18874368, full mode)
static const size_t TOTAL_FULL = 29341696;  // floats (117.4 MB)
static const size_t TOTAL_PERH = 19904512;  // floats; per-h ew aliases dead WK2 region

extern "C" void kernel_launch(void* const* d_in, const int* in_sizes, int n_in,
                              void* d_out, int out_size, void* d_ws, size_t ws_size,
                              hipStream_t stream) {
  (void)in_sizes; (void)n_in; (void)out_size;
  const float* x = (const float*)d_in[0];
  const float* ln_w = (const float*)d_in[1];
  const float* ln_b = (const float*)d_in[2];
  const float* W_abcde = (const float*)d_in[3];
  const float* b_abcde = (const float*)d_in[4];
  const float* W_K = (const float*)d_in[5];
  const float* W_V = (const float*)d_in[6];
  const float* W_out = (const float*)d_in[7];
  const float* b_out = (const float*)d_in[8];
  float* out = (float*)d_out;
  float* ws = (float*)d_ws;

  float* xn = ws + OFF_XN;
  float* proj = ws + OFF_PROJ;
  float* bsum = ws + OFF_BSUM;
  float* wk2 = ws + OFF_WK2;
  float* step1 = ws + OFF_STEP1;
  float* step2 = ws + OFF_STEP2;
  float* tbuf = ws + OFF_T;
  float* ecum = ws + OFF_ECUM;
  float* Vm = ws + OFF_VM;
  float* Lsum = ws + OFF_LSUM;
  float* z = ws + OFF_Z;
  float* Zpart = ws + OFF_ZPART;
  u16* a_bf = (u16*)(ws + OFF_ABF);
  u16* eT_bf = (u16*)(ws + OFF_ETBF);
  u16* s2bf = (u16*)(ws + OFF_S2BF);
  u16* tT_bf = (u16*)(ws + OFF_TTBF);

  bool full = ws_size >= TOTAL_FULL * sizeof(float);
  u16* ew_bf = full ? (u16*)(ws + OFF_EWBF) : (u16*)(ws + OFF_WK2);

  ln_kernel<<<SEQ, 256, 0, stream>>>(x, ln_w, ln_b, xn);
  gemm_kernel<true, true><<<dim3(40, 3, 1), 256, 0, stream>>>(
      xn, W_abcde, proj, b_abcde, 192, 2560, 512, 512, 512, 2560, 0, 0, 0);
  bsum_kernel<<<SEQ, 64, 0, stream>>>(proj, bsum);
  wk2_kernel<<<8192, 256, 0, stream>>>(W_K, wk2);
  gemm_kernel<false, false><<<dim3(64, 3, 1), 256, 0, stream>>>(
      proj + 1024, wk2, step1, nullptr, 192, 4096, 512, 2560, 4096, 4096, 0, 0, 0);
  gemm_kernel<true, false><<<dim3(3, 192, 1), 256, 0, stream>>>(
      step1, bsum, step2, nullptr, 12288, 192, 64, 64, 64, 192, 0, 0, 0);
  gemm_kernel<false, false><<<dim3(64, 3, 8), 256, 0, stream>>>(
      proj + 1536, W_V, tbuf, nullptr, 192, 4096, 64, 2560, 4096, 4096, 64, 262144, 786432);
  ecum_kernel<<<8, 64, 0, stream>>>(proj, ecum);
  hipMemsetAsync(Vm, 0, 512 * sizeof(float), stream);
  vm_kernel<<<dim3(12, 8), 256, 0, stream>>>(tbuf, ecum, Vm);

  conv_ae_kernel<<<dim3(SEQ, 8), 64, 0, stream>>>(proj, a_bf, eT_bf);
  conv_s2_kernel<<<SEQ, 256, 0, stream>>>(step2, s2bf);
  conv_t_kernel<<<dim3(SEQ, 8), 256, 0, stream>>>(tbuf, tT_bf);

  if (full) {
    attn_mfma_kernel<<<dim3(SEQ, 8), 256, 0, stream>>>(a_bf, s2bf, eT_bf, ew_bf, Lsum, 0);
    zgemm_mfma_kernel<<<dim3(8, 32), 256, 0, stream>>>(ew_bf, tT_bf, Zpart, 0);
  } else {
    for (int h = 0; h < 8; h++) {
      attn_mfma_kernel<<<dim3(SEQ, 1), 256, 0, stream>>>(a_bf, s2bf, eT_bf, ew_bf, Lsum, h);
      zgemm_mfma_kernel<<<dim3(1, 32), 256, 0, stream>>>(ew_bf, tT_bf, Zpart, h);
    }
  }
  epi_kernel<<<SEQ, 256, 0, stream>>>(Zpart, Vm, Lsum, z);
  gemm_kernel<true, true><<<dim3(8, 3, 1), 256, 0, stream>>>(
      z, W_out, out, b_out, 192, 512, 512, 512, 512, 512, 0, 0, 0);
}

// Round 3
// 281.576 us; speedup vs baseline: 3.2191x; 1.1511x over previous
//
#include <hip/hip_runtime.h>
#include <hip/hip_bf16.h>
#include <cstdint>

#define SEQ 192
#define PROJ_COLS 2560

typedef float f32x4 __attribute__((ext_vector_type(4)));
typedef __bf16 bf16;
typedef __bf16 bf16x8 __attribute__((ext_vector_type(8)));
typedef __bf16 bf16x4 __attribute__((ext_vector_type(4)));

#define MFMA_BF16(a, b, c) __builtin_amdgcn_mfma_f32_16x16x32_bf16(a, b, c, 0, 0, 0)

// ---------------- LayerNorm -> bf16 ----------------
__global__ void ln_kernel(const float* __restrict__ x, const float* __restrict__ w,
                          const float* __restrict__ b, bf16* __restrict__ xn_bf) {
  int r = blockIdx.x, tid = threadIdx.x;
  const float* xr = x + (size_t)r * 512;
  float v0 = xr[tid], v1 = xr[tid + 256];
  float s = v0 + v1, s2 = v0 * v0 + v1 * v1;
#pragma unroll
  for (int off = 32; off > 0; off >>= 1) {
    s += __shfl_down(s, off);
    s2 += __shfl_down(s2, off);
  }
  __shared__ float redS[4], redS2[4];
  int wave = tid >> 6, lane = tid & 63;
  if (lane == 0) { redS[wave] = s; redS2[wave] = s2; }
  __syncthreads();
  float S = redS[0] + redS[1] + redS[2] + redS[3];
  float S2 = redS2[0] + redS2[1] + redS2[2] + redS2[3];
  float mean = S * (1.0f / 512.0f);
  float var = S2 * (1.0f / 512.0f) - mean * mean;
  float rstd = rsqrtf(var + 1e-5f);
  bf16* xnr = xn_bf + (size_t)r * 512;
  xnr[tid]       = (bf16)((v0 - mean) * rstd * w[tid] + b[tid]);
  xnr[tid + 256] = (bf16)((v1 - mean) * rstd * w[tid + 256] + b[tid + 256]);
}

// ---------------- weight prep: Wab, Wout convert; WK permute+convert ----------------
// WK2t[(i*64+j)*512 + h*64+k] = WK[h][i][j][k]  (both sides k-innermost: coalesced)
__global__ void prep_w_kernel(const float* __restrict__ Wab, const float* __restrict__ Wout,
                              const float* __restrict__ WK, bf16* __restrict__ Wab_bf,
                              bf16* __restrict__ Wout_bf, bf16* __restrict__ WK2t) {
  long idx = (long)blockIdx.x * 256 + threadIdx.x;
  if (idx < 1310720) { Wab_bf[idx] = (bf16)Wab[idx]; return; }
  idx -= 1310720;
  if (idx < 262144) { Wout_bf[idx] = (bf16)Wout[idx]; return; }
  idx -= 262144;
  if (idx < 2097152) {
    long o = idx;
    int k = o & 63, h = (o >> 6) & 7, j = (o >> 9) & 63, i = (int)(o >> 15);
    WK2t[o] = (bf16)WK[(((size_t)(h * 64 + i) * 64 + j) * 64) + k];
  }
}

// ---------------- WVt[h][(g*64+f)*64 + h'] = WV[h][h'][g][f] (LDS transpose) ----------------
__global__ void wvt_kernel(const float* __restrict__ WV, bf16* __restrict__ WVt) {
  int g = blockIdx.x, h = blockIdx.y, tid = threadIdx.x;
  __shared__ float ld[64 * 65];
  int f = tid & 63, r4 = tid >> 6;
#pragma unroll
  for (int it = 0; it < 16; it++) {
    int hp = it * 4 + r4;
    ld[hp * 65 + f] = WV[(((size_t)(h * 64 + hp) * 64 + g) * 64) + f];
  }
  __syncthreads();
  int hp = tid & 63;
#pragma unroll
  for (int it = 0; it < 16; it++) {
    int ff = it * 4 + r4;
    WVt[(size_t)h * 262144 + (size_t)(g * 64 + ff) * 64 + hp] = (bf16)ld[hp * 65 + ff];
  }
}

// ---------------- generic LDS-free bf16 MFMA GEMM: C = A @ Bt^T ----------------
// A [M][K] bf16 row-major, Bt [N][K] bf16 row-major. 64x64 tile, 4 waves = 4 m-strips.
// MODE 0: f32 row-major (+bias). MODE 1: bf16 row-major. MODE 2: s2bf layout
// [m>>6][n][m&63] packed 4-wide. MODE 3: f32 row-major + bf16 transposed tT.
template <int MODE, bool HAS_BIAS>
__global__ __launch_bounds__(256) void mfma_gemm(
    const bf16* __restrict__ A, const bf16* __restrict__ Bt, void* __restrict__ C0,
    bf16* __restrict__ C1, const float* __restrict__ bias, int N, int K,
    long sA, long sB, long sC) {
  int zb = blockIdx.z;
  const bf16* Ab = A + (size_t)zb * sA;
  const bf16* Bb = Bt + (size_t)zb * sB;
  int n0 = blockIdx.x * 64, m0 = blockIdx.y * 64;
  int tid = threadIdx.x, wave = tid >> 6, lane = tid & 63;
  int lq = lane >> 4, l16 = lane & 15;
  const bf16* Ap = Ab + (size_t)(m0 + wave * 16 + l16) * K;
  f32x4 acc[4];
#pragma unroll
  for (int nt = 0; nt < 4; nt++) acc[nt] = (f32x4){0.f, 0.f, 0.f, 0.f};
  for (int k0 = 0; k0 < K; k0 += 32) {
    bf16x8 af = *(const bf16x8*)(Ap + k0 + lq * 8);
#pragma unroll
    for (int nt = 0; nt < 4; nt++) {
      bf16x8 bv = *(const bf16x8*)(Bb + (size_t)(n0 + nt * 16 + l16) * K + k0 + lq * 8);
      acc[nt] = MFMA_BF16(af, bv, acc[nt]);
    }
  }
  int cm = m0 + wave * 16 + lq * 4;
#pragma unroll
  for (int nt = 0; nt < 4; nt++) {
    int n = n0 + nt * 16 + l16;
    if constexpr (MODE == 0) {
      float* C = (float*)C0 + (size_t)zb * sC;
      float bv = HAS_BIAS ? bias[n] : 0.f;
#pragma unroll
      for (int rg = 0; rg < 4; rg++)
        C[(size_t)(cm + rg) * N + n] = acc[nt][rg] + bv;
    } else if constexpr (MODE == 1) {
#pragma unroll
      for (int rg = 0; rg < 4; rg++)
        C1[(size_t)(cm + rg) * N + n] = (bf16)acc[nt][rg];
    } else if constexpr (MODE == 2) {
      int r = cm >> 6, i0 = cm & 63;
      bf16x4 pk = {(bf16)acc[nt][0], (bf16)acc[nt][1], (bf16)acc[nt][2], (bf16)acc[nt][3]};
      *(bf16x4*)(C1 + (size_t)r * 12288 + (size_t)n * 64 + i0) = pk;
    } else {  // MODE 3
      float* C = (float*)C0 + (size_t)zb * sC;
      int g = n >> 6, f = n & 63;
#pragma unroll
      for (int rg = 0; rg < 4; rg++) {
        int p = cm + rg;
        C[(size_t)p * N + n] = acc[nt][rg];
        C1[(size_t)zb * 786432 + (size_t)f * 12288 + (size_t)p * 64 + g] = (bf16)acc[nt][rg];
      }
    }
  }
}

// ---------------- post-proj: extract a,c,d,eT (bf16) + bsum (bf16) ----------------
__global__ void post_proj_kernel(const float* __restrict__ proj, bf16* __restrict__ a_bf,
                                 bf16* __restrict__ c_bf, bf16* __restrict__ d_bf,
                                 bf16* __restrict__ eT_bf, bf16* __restrict__ bsum_bf) {
  int p = blockIdx.x, t = threadIdx.x;  // 512 threads
  int h = t >> 6, i = t & 63;
  const float* pr = proj + (size_t)p * PROJ_COLS;
  a_bf[((size_t)h * SEQ + p) * 64 + i] = (bf16)pr[t];
  c_bf[(size_t)p * 512 + t] = (bf16)pr[1024 + t];
  d_bf[((size_t)h * SEQ + p) * 64 + i] = (bf16)pr[1536 + t];
  eT_bf[((size_t)h * 64 + i) * SEQ + p] = (bf16)pr[2048 + t];
  if (t < 64) {
    float s = 0.f;
#pragma unroll
    for (int hh = 0; hh < 8; hh++) s += pr[512 + hh * 64 + t];
    bsum_bf[p * 64 + t] = (bf16)s;
  }
}

// ---------------- ecum[h][p][g] = sum_{q<=p} e[q,h,g] (f32 from proj) ----------------
__global__ void ecum_kernel(const float* __restrict__ proj, float* __restrict__ ecum) {
  int h = blockIdx.x, g = threadIdx.x;
  float run = 0.f;
  for (int p = 0; p < SEQ; p++) {
    run += proj[(size_t)p * PROJ_COLS + 2048 + h * 64 + g];
    ecum[((size_t)h * SEQ + p) * 64 + g] = run;
  }
}

// ---------------- Vm[h][f] = sum_{p,g} t[h,p,g,f] * ecum[h,p,g] ----------------
__global__ void vm_kernel(const float* __restrict__ t, const float* __restrict__ ecum,
                          float* __restrict__ Vm) {
  int pt = blockIdx.x, h = blockIdx.y;
  int tid = threadIdx.x, f = tid & 63, gg = tid >> 6;
  float acc = 0.f;
  for (int pp = 0; pp < 16; pp++) {
    int p = pt * 16 + pp;
    const float* tp = t + ((size_t)(h * SEQ + p) * 64) * 64;
    const float* ep = ecum + (size_t)(h * SEQ + p) * 64;
#pragma unroll
    for (int gi = 0; gi < 16; gi++) {
      int g = gg * 16 + gi;
      acc += tp[g * 64 + f] * ep[g];
    }
  }
  __shared__ float red[256];
  red[tid] = acc;
  __syncthreads();
  if (gg == 0) {
    float s = red[f] + red[64 + f] + red[128 + f] + red[192 + f];
    atomicAdd(&Vm[h * 64 + f], s);
  }
}

// ---------------- MFMA fused scores+exp+ew per (h, r) ----------------
// Wave w owns p-tiles {w, w+4, 11-w} (load-balanced vs causal mask).
// Fully-masked 16x16 subtiles (qtile < ptile) skip MFMA+exp, store zeros.
// ew k-chunks with all-zero w (chunk qmax <= ptile*16) skip MFMA entirely.
__global__ __launch_bounds__(256) void attn_mfma_kernel(
    const bf16* __restrict__ a_bf, const bf16* __restrict__ s2bf,
    const bf16* __restrict__ eT_bf, bf16* __restrict__ ew_bf,
    float* __restrict__ Lsum, int h0) {
  int r = blockIdx.x, hb = blockIdx.y, h = h0 + hb;
  int tid = threadIdx.x, wave = tid >> 6, lane = tid & 63;
  int lq = lane >> 4, l16 = lane & 15;
  __shared__ bf16 w_s[SEQ * 72];  // stride 72 elems = 144B (16B-aligned frag rows)
  __shared__ float redL[4];
  int pt[3] = {wave, wave + 4, 11 - wave};

  bf16x8 afr[3][2];
  const bf16* ab = a_bf + (size_t)h * SEQ * 64;
#pragma unroll
  for (int mt = 0; mt < 3; mt++)
#pragma unroll
    for (int kc = 0; kc < 2; kc++) {
      int p = pt[mt] * 16 + l16;
      afr[mt][kc] = *(const bf16x8*)(ab + p * 64 + kc * 32 + lq * 8);
    }

  f32x4 ewacc[3][4];
#pragma unroll
  for (int mt = 0; mt < 3; mt++)
#pragma unroll
    for (int nt = 0; nt < 4; nt++) ewacc[mt][nt] = (f32x4){0.f, 0.f, 0.f, 0.f};

  float lpart = 0.f;
  const bf16* s2r = s2bf + (size_t)r * 12288;
  const bf16* eh = eT_bf + (size_t)h * 64 * SEQ;

  for (int qt = 0; qt < 3; qt++) {
    bf16x8 bfr[4][2];
#pragma unroll
    for (int nt = 0; nt < 4; nt++)
#pragma unroll
      for (int kc = 0; kc < 2; kc++) {
        int q = qt * 64 + nt * 16 + l16;
        bfr[nt][kc] = *(const bf16x8*)(s2r + q * 64 + kc * 32 + lq * 8);
      }
#pragma unroll
    for (int mt = 0; mt < 3; mt++) {
      int ptile = pt[mt];
      int pbase = ptile * 16 + lq * 4;
#pragma unroll
      for (int nt = 0; nt < 4; nt++) {
        int qtile = qt * 4 + nt;
        if (qtile < ptile) {  // fully masked: w = 0
#pragma unroll
          for (int rg = 0; rg < 4; rg++) w_s[(pbase + rg) * 72 + nt * 16 + l16] = (bf16)0.f;
          continue;
        }
        f32x4 s = (f32x4){0.f, 0.f, 0.f, 0.f};
        s = MFMA_BF16(afr[mt][0], bfr[nt][0], s);
        s = MFMA_BF16(afr[mt][1], bfr[nt][1], s);
        int q = qt * 64 + nt * 16 + l16;
#pragma unroll
        for (int rg = 0; rg < 4; rg++) {
          int p = pbase + rg;
          float wv = (q > p) ? __expf(s[rg] * 0.015625f) : 0.f;
          lpart += wv;
          w_s[p * 72 + nt * 16 + l16] = (bf16)wv;
        }
      }
    }
    bf16x8 efr[4][2];
#pragma unroll
    for (int nt = 0; nt < 4; nt++)
#pragma unroll
      for (int kc = 0; kc < 2; kc++) {
        int g = nt * 16 + l16;
        efr[nt][kc] = *(const bf16x8*)(eh + g * SEQ + qt * 64 + kc * 32 + lq * 8);
      }
#pragma unroll
    for (int mt = 0; mt < 3; mt++) {
      int p = pt[mt] * 16 + l16;
#pragma unroll
      for (int kc = 0; kc < 2; kc++) {
        if (qt * 64 + kc * 32 + 31 <= pt[mt] * 16) continue;  // all-zero w chunk
        bf16x8 wf = *(const bf16x8*)(&w_s[p * 72 + kc * 32 + lq * 8]);
#pragma unroll
        for (int nt = 0; nt < 4; nt++)
          ewacc[mt][nt] = MFMA_BF16(wf, efr[nt][kc], ewacc[mt][nt]);
      }
    }
  }

  bf16* ewout = ew_bf + ((size_t)hb * SEQ + r) * 12288;
#pragma unroll
  for (int mt = 0; mt < 3; mt++)
#pragma unroll
    for (int nt = 0; nt < 4; nt++)
#pragma unroll
      for (int rg = 0; rg < 4; rg++) {
        int p = pt[mt] * 16 + lq * 4 + rg;
        int g = nt * 16 + l16;
        ewout[p * 64 + g] = (bf16)ewacc[mt][nt][rg];
      }

#pragma unroll
  for (int off = 32; off > 0; off >>= 1) lpart += __shfl_down(lpart, off);
  if (lane == 0) redL[wave] = lpart;
  __syncthreads();
  if (tid == 0) Lsum[h * SEQ + r] = redL[0] + redL[1] + redL[2] + redL[3];
}

// ---------------- MFMA split-K z GEMM: Zpart[h][ks] = ew @ tT ----------------
__global__ __launch_bounds__(256) void zgemm_mfma_kernel(
    const bf16* __restrict__ ew_bf, const bf16* __restrict__ tT_bf,
    float* __restrict__ Zpart, int h0) {
  int hb = blockIdx.x, ks = blockIdx.y, h = h0 + hb;
  int tid = threadIdx.x, wave = tid >> 6, lane = tid & 63;
  int lq = lane >> 4, l16 = lane & 15;
  f32x4 acc[3][4];
#pragma unroll
  for (int mt = 0; mt < 3; mt++)
#pragma unroll
    for (int nt = 0; nt < 4; nt++) acc[mt][nt] = (f32x4){0.f, 0.f, 0.f, 0.f};
  const bf16* ewb = ew_bf + (size_t)hb * SEQ * 12288;
  const bf16* tb = tT_bf + (size_t)h * 64 * 12288;
  for (int kc = 0; kc < 12; kc++) {
    int kbase = ks * 384 + kc * 32 + lq * 8;
    bf16x8 af[3], bf_[4];
#pragma unroll
    for (int mt = 0; mt < 3; mt++) {
      int rr = wave * 48 + mt * 16 + l16;
      af[mt] = *(const bf16x8*)(ewb + (size_t)rr * 12288 + kbase);
    }
#pragma unroll
    for (int nt = 0; nt < 4; nt++) {
      int f = nt * 16 + l16;
      bf_[nt] = *(const bf16x8*)(tb + (size_t)f * 12288 + kbase);
    }
#pragma unroll
    for (int mt = 0; mt < 3; mt++)
#pragma unroll
      for (int nt = 0; nt < 4; nt++)
        acc[mt][nt] = MFMA_BF16(af[mt], bf_[nt], acc[mt][nt]);
  }
  float* zp = Zpart + ((size_t)(h * 32 + ks) * SEQ) * 64;
#pragma unroll
  for (int mt = 0; mt < 3; mt++)
#pragma unroll
    for (int nt = 0; nt < 4; nt++)
#pragma unroll
      for (int rg = 0; rg < 4; rg++) {
        int rr = wave * 48 + mt * 16 + lq * 4 + rg;
        int f = nt * 16 + l16;
        zp[(size_t)rr * 64 + f] = acc[mt][nt][rg];
      }
}

// ---------------- epilogue: z_bf = (sum_ks Zpart + Vm) / (Lsum + 18528) ----------------
__global__ void epi_kernel(const float* __restrict__ Zpart, const float* __restrict__ Vm,
                           const float* __restrict__ Lsum, bf16* __restrict__ z_bf) {
  int r = blockIdx.x, tid = threadIdx.x;
  for (int c = tid; c < 512; c += 256) {
    int h = c >> 6, f = c & 63;
    float s = 0.f;
    for (int ks = 0; ks < 32; ks++)
      s += Zpart[(((size_t)h * 32 + ks) * SEQ + r) * 64 + f];
    float L = Lsum[h * SEQ + r] + 18528.0f;  // masked mass: 18528 entries with w == 1.0f
    z_bf[(size_t)r * 512 + c] = (bf16)((s + Vm[c]) / L);
  }
}

// ---------------- workspace layout (f32 units; bf16 buffers count as half) ----------------
static const size_t OFF_PROJ = 0;            // f32 491520
static const size_t OFF_S1BF = 491520;       // bf16 786432 -> 393216
static const size_t OFF_S2BF = 884736;       // bf16 2359296 -> 1179648
static const size_t OFF_XNBF = 2064384;      // 49152
static const size_t OFF_WABBF = 2113536;     // 655360
static const size_t OFF_WOUTBF = 2768896;    // 131072
static const size_t OFF_WK2TBF = 2899968;    // 1048576
static const size_t OFF_WVTBF = 3948544;     // 1048576
static const size_t OFF_CBF = 4997120;       // 49152
static const size_t OFF_DBF = 5046272;       // 49152
static const size_t OFF_ABF = 5095424;       // 49152
static const size_t OFF_ETBF = 5144576;      // 49152
static const size_t OFF_BSUMBF = 5193728;    // 6144
static const size_t OFF_T = 5199872;         // f32 6291456
static const size_t OFF_TTBF = 11491328;     // bf16 6291456 -> 3145728
static const size_t OFF_ECUM = 14637056;     // 98304
static const size_t OFF_VM = 14735360;       // 512
static const size_t OFF_LSUM = 14735872;     // 1536
static const size_t OFF_ZBF = 14737408;      // 49152
static const size_t OFF_ZPART = 14786560;    // 3145728
static const size_t OFF_EWBF = 17932288;     // bf16 18874368 -> 9437184 (full mode)
static const size_t TOTAL_FULL = 27369472;   // f32 units = 109.5 MB
// per-h fallback: ew (192*12288 bf16 = 1179648 f32) aliases WK2T region (dead by then)

extern "C" void kernel_launch(void* const* d_in, const int* in_sizes, int n_in,
                              void* d_out, int out_size, void* d_ws, size_t ws_size,
                              hipStream_t stream) {
  (void)in_sizes; (void)n_in; (void)out_size;
  const float* x = (const float*)d_in[0];
  const float* ln_w = (const float*)d_in[1];
  const float* ln_b = (const float*)d_in[2];
  const float* W_abcde = (const float*)d_in[3];
  const float* b_abcde = (const float*)d_in[4];
  const float* W_K = (const float*)d_in[5];
  const float* W_V = (const float*)d_in[6];
  const float* W_out = (const float*)d_in[7];
  const float* b_out = (const float*)d_in[8];
  float* out = (float*)d_out;
  float* ws = (float*)d_ws;

  float* proj = ws + OFF_PROJ;
  bf16* s1bf = (bf16*)(ws + OFF_S1BF);
  bf16* s2bf = (bf16*)(ws + OFF_S2BF);
  bf16* xn_bf = (bf16*)(ws + OFF_XNBF);
  bf16* Wab_bf = (bf16*)(ws + OFF_WABBF);
  bf16* Wout_bf = (bf16*)(ws + OFF_WOUTBF);
  bf16* WK2t = (bf16*)(ws + OFF_WK2TBF);
  bf16* WVt = (bf16*)(ws + OFF_WVTBF);
  bf16* c_bf = (bf16*)(ws + OFF_CBF);
  bf16* d_bf = (bf16*)(ws + OFF_DBF);
  bf16* a_bf = (bf16*)(ws + OFF_ABF);
  bf16* eT_bf = (bf16*)(ws + OFF_ETBF);
  bf16* bsum_bf = (bf16*)(ws + OFF_BSUMBF);
  float* tbuf = ws + OFF_T;
  bf16* tT_bf = (bf16*)(ws + OFF_TTBF);
  float* ecum = ws + OFF_ECUM;
  float* Vm = ws + OFF_VM;
  float* Lsum = ws + OFF_LSUM;
  bf16* z_bf = (bf16*)(ws + OFF_ZBF);
  float* Zpart = ws + OFF_ZPART;

  bool full = ws_size >= TOTAL_FULL * sizeof(float);
  bf16* ew_bf = full ? (bf16*)(ws + OFF_EWBF) : (bf16*)(ws + OFF_WK2TBF);

  // weight prep (1310720 + 262144 + 2097152 = 3670016 elems)
  prep_w_kernel<<<14336, 256, 0, stream>>>(W_abcde, W_out, W_K, Wab_bf, Wout_bf, WK2t);
  wvt_kernel<<<dim3(64, 8), 256, 0, stream>>>(W_V, WVt);
  ln_kernel<<<SEQ, 256, 0, stream>>>(x, ln_w, ln_b, xn_bf);
  // proj = xn @ Wab^T + b  [192 x 2560], f32
  mfma_gemm<0, true><<<dim3(40, 3, 1), 256, 0, stream>>>(
      xn_bf, Wab_bf, proj, nullptr, b_abcde, 2560, 512, 0, 0, 0);
  post_proj_kernel<<<SEQ, 512, 0, stream>>>(proj, a_bf, c_bf, d_bf, eT_bf, bsum_bf);
  ecum_kernel<<<8, 64, 0, stream>>>(proj, ecum);
  // step1 = c @ WK2t^T  [192 x 4096] -> bf16 row-major (== [12288][64] for step2 A)
  mfma_gemm<1, false><<<dim3(64, 3, 1), 256, 0, stream>>>(
      c_bf, WK2t, nullptr, s1bf, nullptr, 4096, 512, 0, 0, 0);
  // step2: [12288 x 192] K=64 -> s2bf[r][q][i] bf16 direct
  mfma_gemm<2, false><<<dim3(3, 192, 1), 256, 0, stream>>>(
      s1bf, bsum_bf, nullptr, s2bf, nullptr, 192, 64, 0, 0, 0);
  // t[h] = d_h @ WVt[h]^T  [192 x 4096] x8 -> f32 t + bf16 tT
  mfma_gemm<3, false><<<dim3(64, 3, 8), 256, 0, stream>>>(
      d_bf, WVt, tbuf, tT_bf, nullptr, 4096, 64, 12288, 262144, 786432);
  hipMemsetAsync(Vm, 0, 512 * sizeof(float), stream);
  vm_kernel<<<dim3(12, 8), 256, 0, stream>>>(tbuf, ecum, Vm);

  if (full) {
    attn_mfma_kernel<<<dim3(SEQ, 8), 256, 0, stream>>>(a_bf, s2bf, eT_bf, ew_bf, Lsum, 0);
    zgemm_mfma_kernel<<<dim3(8, 32), 256, 0, stream>>>(ew_bf, tT_bf, Zpart, 0);
  } else {
    for (int h = 0; h < 8; h++) {
      attn_mfma_kernel<<<dim3(SEQ, 1), 256, 0, stream>>>(a_bf, s2bf, eT_bf, ew_bf, Lsum, h);
      zgemm_mfma_kernel<<<dim3(1, 32), 256, 0, stream>>>(ew_bf, tT_bf, Zpart, h);
    }
  }
  epi_kernel<<<SEQ, 256, 0, stream>>>(Zpart, Vm, Lsum, z_bf);
  // out = z @ W_out^T + b_out  [192 x 512]
  mfma_gemm<0, true><<<dim3(8, 3, 1), 256, 0, stream>>>(
      z_bf, Wout_bf, out, nullptr, b_out, 512, 512, 0, 0, 0);
}